// Round 15
// baseline (351.557 us; speedup 1.0000x reference)
//
#include <hip/hip_runtime.h>

typedef unsigned short u16;
typedef unsigned int   u32;
typedef int   v4i __attribute__((ext_vector_type(4)));
typedef float v4f __attribute__((ext_vector_type(4)));

// ---------- helpers ----------
__device__ __forceinline__ float b2f(u16 v) {
    union { unsigned u; float f; } t; t.u = ((unsigned)v) << 16; return t.f;
}
__device__ __forceinline__ u16 f2b(float f) {
    union { float f; unsigned u; } t; t.f = f;
    unsigned r = (t.u + 0x7FFFu + ((t.u >> 16) & 1u)) >> 16;
    return (u16)r;
}
__device__ __forceinline__ u16 f2b_trunc(float f) {
    union { float f; unsigned u; } t; t.f = f;
    return (u16)(t.u >> 16);
}
__device__ __forceinline__ v4f mfma16(v4i a, v4i b, v4f c) {
    asm("v_mfma_f32_16x16x32_bf16 %0, %1, %2, %0" : "+v"(c) : "v"(a), "v"(b));
    return c;
}
__device__ __forceinline__ void gload16(const u16* g, u16* l) {
    __builtin_amdgcn_global_load_lds(
        (const __attribute__((address_space(1))) unsigned int*)g,
        (__attribute__((address_space(3))) unsigned int*)l,
        16, 0, 0);
}

// ---------- weight f32->bf16 convert (plain) ----------
struct WCvt { const float* s[9]; u16* d[9]; int n[9]; };
__global__ void cvt_weights(WCvt p) {
    int wi = blockIdx.y;
    int i = blockIdx.x * 256 + threadIdx.x;
    if (i < p.n[wi]) p.d[wi][i] = f2b(p.s[wi][i]);
}

// ---------- transposed convert (256x256): Win1, Win3, Wv ----------
__global__ void cvt_t(const float* __restrict__ W1, const float* __restrict__ W3,
                      const float* __restrict__ Wv,
                      u16* __restrict__ T1, u16* __restrict__ T3, u16* __restrict__ Tv)
{
    const int zz = blockIdx.z;
    const float* src = (zz == 0) ? W1 : (zz == 1) ? W3 : Wv;
    u16* dst = (zz == 0) ? T1 : (zz == 1) ? T3 : Tv;
    __shared__ float t[32][33];
    const int r0 = blockIdx.x * 32, c0 = blockIdx.y * 32;
    const int tx = threadIdx.x, ty = threadIdx.y;
#pragma unroll
    for (int i = 0; i < 4; i++)
        t[ty + i * 8][tx] = src[(long)(r0 + ty + i * 8) * 256 + c0 + tx];
    __syncthreads();
#pragma unroll
    for (int i = 0; i < 4; i++)
        dst[(long)(c0 + ty + i * 8) * 256 + r0 + tx] = f2b(t[tx][ty + i * 8]);
}

// ---------- bias folds (parallel reductions) ----------
__global__ void bias_btr(const float* __restrict__ Wtr, const float* __restrict__ bin1,
                         const float* __restrict__ bin3, const float* __restrict__ btr,
                         float* __restrict__ btr_eff)
{
    const int j = blockIdx.x, k = threadIdx.x;   // 512 x 256
    float v = Wtr[(long)j * 512 + k] * bin1[k] + Wtr[(long)j * 512 + 256 + k] * bin3[k];
    v += __shfl_xor(v, 1); v += __shfl_xor(v, 2); v += __shfl_xor(v, 4);
    v += __shfl_xor(v, 8); v += __shfl_xor(v, 16); v += __shfl_xor(v, 32);
    __shared__ float part[4];
    if ((k & 63) == 0) part[k >> 6] = v;
    __syncthreads();
    if (k == 0) btr_eff[j] = btr[j] + part[0] + part[1] + part[2] + part[3];
}

__global__ void bias_r56(const float* __restrict__ Wout2, const float* __restrict__ Wout3,
                         const float* __restrict__ bout2, const float* __restrict__ bout3,
                         const float* __restrict__ btr_eff,
                         float* __restrict__ r5, float* __restrict__ r6)
{
    const int j = blockIdx.x, k = threadIdx.x;   // 512 x 256
    float v = (j < 256) ? Wout2[(long)j * 256 + k] * btr_eff[k]
                        : Wout3[(long)(j - 256) * 256 + k] * btr_eff[256 + k];
    v += __shfl_xor(v, 1); v += __shfl_xor(v, 2); v += __shfl_xor(v, 4);
    v += __shfl_xor(v, 8); v += __shfl_xor(v, 16); v += __shfl_xor(v, 32);
    __shared__ float part[4];
    if ((k & 63) == 0) part[k >> 6] = v;
    __syncthreads();
    if (k == 0) {
        float s = part[0] + part[1] + part[2] + part[3];
        if (j < 256) r5[j] = bout2[j] + s;
        else         r6[j - 256] = bout3[j - 256] + s;
    }
}

// ---------- transpose+convert x,y ----------
__global__ __launch_bounds__(256) void transpose_cvt(
    const float* __restrict__ x, const float* __restrict__ y,
    u16* __restrict__ xt, u16* __restrict__ yt)
{
    const int z = blockIdx.z, t = z >> 2, b = z & 3;
    const float* src = t ? y : x;
    u16* dst = t ? yt : xt;
    __shared__ float tile[32][33];
    const int nt = blockIdx.x * 32, ct = blockIdx.y * 32;
    const int tx = threadIdx.x, ty = threadIdx.y;
#pragma unroll
    for (int i = 0; i < 4; i++)
        tile[ty + i * 8][tx] = src[((long)b * 256 + ct + ty + i * 8) * 4096 + nt + tx];
    __syncthreads();
#pragma unroll
    for (int i = 0; i < 4; i++)
        dst[((long)b * 4096 + nt + ty + i * 8) * 256 + ct + tx] = f2b(tile[tx][ty + i * 8]);
}

// ---------- small path ----------
__global__ void small_zm(const float* __restrict__ z, const float* __restrict__ m,
                         const float* __restrict__ Wv, const float* __restrict__ Wfc,
                         const float* __restrict__ bfc,
                         float* __restrict__ zv, float* __restrict__ mline)
{
    const int o = blockIdx.x, b = blockIdx.y, tid = threadIdx.x; // block 64
    __shared__ float wrow[256];
    __shared__ float mvs[9];
    for (int i = tid; i < 256; i += 64) wrow[i] = Wv[o * 256 + i];
    __syncthreads();
    if (tid < 36) {
        float s = 0.f;
        for (int c = 0; c < 256; c++) s += wrow[c] * z[((long)b * 256 + c) * 36 + tid];
        zv[((long)b * 256 + o) * 36 + tid] = s;
    }
    if (tid < 9) {
        float s = 0.f;
        for (int c = 0; c < 256; c++) s += wrow[c] * m[((long)b * 256 + c) * 9 + tid];
        mvs[tid] = s;
    }
    __syncthreads();
    if (tid < 36) {
        float s = bfc[tid];
        for (int k = 0; k < 9; k++) s += mvs[k] * Wfc[tid * 9 + k];
        mline[((long)b * 256 + o) * 36 + tid] = s;
    }
}

__global__ void small_F(const float* __restrict__ zv, const float* __restrict__ mline,
                        u16* __restrict__ Fb, u16* __restrict__ FbT)
{
    const int c = blockIdx.x, b = blockIdx.y, d = threadIdx.x;
    const float* zr = zv + ((long)b * 256 + c) * 36;
    const float* mr = mline + ((long)b * 256 + d) * 36;
    float s = (c == d) ? 1.f : 0.f;
    for (int n = 0; n < 36; n++) s += zr[n] * mr[n];
    u16 v = f2b(s);
    Fb[((long)b * 256 + c) * 256 + d] = v;
    FbT[((long)b * 256 + d) * 256 + c] = v;
}

// ---------- merged GEMM: LDS-staged (m97 structure), BK=32, dbuf ----------
struct GDesc {
    const u16* X; const u16* W; const float* bias;
    u16* outT; u16* outN;
    long xbs, wbs, otbs, onbs;
    int ldx, ldw, ldot, ldon, K, rows;
};
struct GJob { GDesc d[12]; int oblk; };

__global__ __launch_bounds__(256) void gemm_tn(GJob j) {
    const int di = blockIdx.y / j.oblk;
    const int o0 = (blockIdx.y % j.oblk) * 128;
    const GDesc g = j.d[di];
    const int b = blockIdx.z;
    const int n0 = blockIdx.x * 128;
    if (n0 >= g.rows) return;
    const int tid = threadIdx.x, lane = tid & 63, w = tid >> 6;
    const int l15 = lane & 15, lg = lane >> 4;
    const int wr = (w >> 1) * 64, wc = (w & 1) * 64;

    __shared__ __align__(16) u16 As[2][4096];   // 128 x 32 bf16, dbuf (16 KB)
    __shared__ __align__(16) u16 Bs[2][4096];   // 128 x 32 bf16, dbuf (16 KB)

    const int sr = w * 32 + (lane >> 2);
    const int sc = (lane & 3) * 8;
    const u16* Xb_ = g.X + b * g.xbs;
    const u16* Wp_ = g.W + b * g.wbs;

    auto STAGE = [&](int buf, int ks) {
#pragma unroll
        for (int i = 0; i < 2; i++) {
            gload16(Xb_ + (long)(n0 + sr + i * 16) * g.ldx + ks * 32 + sc,
                    &As[buf][w * 1024 + i * 512]);
            gload16(Wp_ + (long)(o0 + sr + i * 16) * g.ldw + ks * 32 + sc,
                    &Bs[buf][w * 1024 + i * 512]);
        }
    };

    v4f acc[4][4];
    for (int oi = 0; oi < 4; oi++) {
        float bv = g.bias ? g.bias[o0 + wc + oi * 16 + l15] : 0.f;
        for (int mi = 0; mi < 4; mi++) acc[mi][oi] = (v4f){bv, bv, bv, bv};
    }

    const int steps = g.K >> 5;
    STAGE(0, 0);
    __syncthreads();
    for (int ks = 0; ks < steps; ks++) {
        const int cur = ks & 1;
        if (ks + 1 < steps) STAGE(cur ^ 1, ks + 1);
        v4i a[4], bb[4];
#pragma unroll
        for (int mi = 0; mi < 4; mi++)
            a[mi] = *(const v4i*)&As[cur][(wr + mi * 16 + l15) * 32 + lg * 8];
#pragma unroll
        for (int oi = 0; oi < 4; oi++)
            bb[oi] = *(const v4i*)&Bs[cur][(wc + oi * 16 + l15) * 32 + lg * 8];
#pragma unroll
        for (int mi = 0; mi < 4; mi++)
#pragma unroll
            for (int oi = 0; oi < 4; oi++)
                acc[mi][oi] = mfma16(a[mi], bb[oi], acc[mi][oi]);
        __syncthreads();
    }

    for (int mi = 0; mi < 4; mi++)
        for (int oi = 0; oi < 4; oi++) {
            int nn = n0 + wr + mi * 16 + lg * 4;
            int oo = o0 + wc + oi * 16 + l15;
            if (g.outT) {
                u16* p = g.outT + b * g.otbs + (long)nn * g.ldot + oo;
#pragma unroll
                for (int r = 0; r < 4; r++) p[(long)r * g.ldot] = f2b(acc[mi][oi][r]);
            }
            if (g.outN) {
                ushort4 pk;
                pk.x = f2b(acc[mi][oi][0]); pk.y = f2b(acc[mi][oi][1]);
                pk.z = f2b(acc[mi][oi][2]); pk.w = f2b(acc[mi][oi][3]);
                *(ushort4*)(g.outN + b * g.onbs + (long)oo * g.ldon + nn) = pk;
            }
        }
}

// ---------- fused attention (r9 main loop) + in-kernel Q projection prologue ----------
__global__ __launch_bounds__(256) void attn_kernel(
    const u16* __restrict__ xt,
    const u16* __restrict__ WqA, const float* __restrict__ bqA,
    const u16* __restrict__ WqB, const float* __restrict__ bqB,
    const u16* __restrict__ ktA, const u16* __restrict__ vA,
    u16* __restrict__ otA, u16* __restrict__ onA, const float* __restrict__ gA,
    const u16* __restrict__ ktB, const u16* __restrict__ vB,
    u16* __restrict__ otB, u16* __restrict__ onB, const float* __restrict__ gB)
{
    // XCD swizzle: all 64 q-blocks of one (branch,batch) share an XCD (wgid%8)
    const int wg = blockIdx.x;
    const int qb = wg >> 3, code = wg & 7;
    const int br = code & 1, b = code >> 1;
    const u16* Kt = br ? ktB : ktA;
    const u16* V  = br ? vB  : vA;
    u16* Ot = br ? otB : otA;
    u16* On = br ? onB : onA;
    const u16* Wq = br ? WqB : WqA;
    const float* bq = br ? bqB : bqA;
    const float gamma = br ? gB[0] : gA[0];
    const long bs = (long)4096 * 256;
    const u16* Kb = Kt + b * bs;
    const u16* Vb = V + b * bs;
    u16* Otb = Ot + b * bs;
    u16* Onb = On + b * bs;

    const int tid = threadIdx.x, lane = tid & 63, w = tid >> 6;
    const int l15 = lane & 15, lg = lane >> 4;

    __shared__ __align__(16) u16 Ksh[4][8192];   // 4 x (32x256 bf16) = 64KB
    __shared__ __align__(16) u16 P[2][64][56];   // dbuf, 112B rows
    __shared__ float den[64];

    // ---- Q projection prologue: Q = xt_tile * Wq^T + bq (LDS scratch in Ksh) ----
    u16* Qs = &Ksh[0][0];                        // 64 x 264 u16 = 33.8KB, aliases Ksh
    {
        v4f qacc[16];
#pragma unroll
        for (int ci = 0; ci < 16; ci++) {
            float bv = bq[ci * 16 + l15];
            qacc[ci] = (v4f){bv, bv, bv, bv};
        }
        const u16* xa = xt + b * bs + (long)(qb * 64 + w * 16 + l15) * 256 + lg * 8;
        const u16* wqp = Wq + (long)l15 * 256 + lg * 8;
#pragma unroll
        for (int ks = 0; ks < 8; ks++) {
            v4i af = *(const v4i*)(xa + ks * 32);
#pragma unroll
            for (int ci = 0; ci < 16; ci++) {
                v4i bf = *(const v4i*)(wqp + (long)ci * 16 * 256 + ks * 32);
                qacc[ci] = mfma16(af, bf, qacc[ci]);
            }
        }
#pragma unroll
        for (int ci = 0; ci < 16; ci++)
#pragma unroll
            for (int r = 0; r < 4; r++)
                Qs[(w * 16 + lg * 4 + r) * 264 + ci * 16 + l15] = f2b(qacc[ci][r]);
    }
    __syncthreads();
    v4i qf[8];
#pragma unroll
    for (int ks = 0; ks < 8; ks++)
        qf[ks] = *(const v4i*)(Qs + (long)(w * 16 + l15) * 264 + ks * 32 + lg * 8);
    asm volatile("s_waitcnt lgkmcnt(0)" ::: "memory");   // qf retired before staging overwrites Ksh
    __builtin_amdgcn_s_barrier();
    __builtin_amdgcn_sched_barrier(0);

    v4f oacc[4][4];
    for (int ci = 0; ci < 4; ci++)
        for (int qi = 0; qi < 4; qi++) oacc[ci][qi] = (v4f){0.f, 0.f, 0.f, 0.f};
    float dacc[4] = {0.f, 0.f, 0.f, 0.f};

    const u16* vb = Vb + (long)(w * 64 + l15) * 4096 + lg * 8;
    v4i vfA[4], vfB[4];

    const int srow = w * 8 + (lane >> 5);
    const int scolB = (lane & 31) * 16;

    auto STAGE = [&](int buf, int t) {
        const u16* base = Kb + (long)t * 8192;
        u16* lb = &Ksh[buf][w * 2048];
#pragma unroll
        for (int i = 0; i < 4; i++) {
            int row = srow + i * 2;
            int colB = scolB ^ ((row & 7) << 4);   // inverse swizzle on SOURCE
            gload16(base + row * 256 + (colB >> 1), lb + i * 512);
        }
    };
    auto VLOAD = [&](v4i (&vf)[4], int t) {
#pragma unroll
        for (int ci = 0; ci < 4; ci++)
            vf[ci] = *(const v4i*)(vb + (long)ci * 16 * 4096 + t * 32);
    };

    STAGE(0, 0);
    STAGE(1, 1);
    STAGE(2, 2);
    VLOAD(vfA, 0);
    asm volatile("s_waitcnt vmcnt(12)" ::: "memory");  // STAGE(0) complete
    __builtin_amdgcn_s_barrier();
    __builtin_amdgcn_sched_barrier(0);

    auto ITER = [&](int mb, v4i (&vcur)[4], v4i (&vnxt)[4]) {
        const u16* kb = &Ksh[mb & 3][0];
        u16* Pc = &P[mb & 1][0][0];

        // QK^T: L[16 own q][32 m], 4 independent chains
        v4f l0a = {0,0,0,0}, l0b = {0,0,0,0}, l1a = {0,0,0,0}, l1b = {0,0,0,0};
        __builtin_amdgcn_s_setprio(1);
#pragma unroll
        for (int ks = 0; ks < 4; ks++) {
            int c0 = (ks * 64 + lg * 16) ^ ((l15 & 7) << 4);   // swizzled READ
            v4i k0 = *(const v4i*)(kb + l15 * 256 + (c0 >> 1));
            v4i k1 = *(const v4i*)(kb + (16 + l15) * 256 + (c0 >> 1));
            l0a = mfma16(qf[ks], k0, l0a);
            l1a = mfma16(qf[ks], k1, l1a);
        }
#pragma unroll
        for (int ks = 4; ks < 8; ks++) {
            int c0 = (ks * 64 + lg * 16) ^ ((l15 & 7) << 4);
            v4i k0 = *(const v4i*)(kb + l15 * 256 + (c0 >> 1));
            v4i k1 = *(const v4i*)(kb + (16 + l15) * 256 + (c0 >> 1));
            l0b = mfma16(qf[ks], k0, l0b);
            l1b = mfma16(qf[ks], k1, l1b);
        }
        __builtin_amdgcn_s_setprio(0);
        v4f lacc0 = l0a + l0b, lacc1 = l1a + l1b;

        // exp -> P (b16 stores), denominator accumulation
#pragma unroll
        for (int r = 0; r < 4; r++) {
            float e0 = __expf(lacc0[r]);
            float e1 = __expf(lacc1[r]);
            dacc[r] += e0 + e1;
            Pc[(w * 16 + lg * 4 + r) * 56 + l15]      = f2b_trunc(e0);
            Pc[(w * 16 + lg * 4 + r) * 56 + 16 + l15] = f2b_trunc(e1);
        }

        // prefetch: V one iter ahead (regs), K three iters ahead (LDS)
        if (mb < 127) VLOAD(vnxt, mb + 1);
        if (mb < 125) STAGE((mb + 3) & 3, mb + 3);

        // single barrier: seal P (lgkm) + STAGE(mb+1) complete (counted vmcnt)
        if (mb <= 124)      asm volatile("s_waitcnt vmcnt(12) lgkmcnt(0)" ::: "memory");
        else if (mb == 125) asm volatile("s_waitcnt vmcnt(8) lgkmcnt(0)" ::: "memory");
        else if (mb == 126) asm volatile("s_waitcnt vmcnt(4) lgkmcnt(0)" ::: "memory");
        else                asm volatile("s_waitcnt vmcnt(0) lgkmcnt(0)" ::: "memory");
        __builtin_amdgcn_s_barrier();
        __builtin_amdgcn_sched_barrier(0);

        // PV: wave w owns channels [w*64, +64), k-dim = 32 keys
        v4i pf[4];
#pragma unroll
        for (int qi = 0; qi < 4; qi++)
            pf[qi] = *(const v4i*)(Pc + (qi * 16 + l15) * 56 + lg * 8);
        __builtin_amdgcn_s_setprio(1);
#pragma unroll
        for (int ci = 0; ci < 4; ci++)
#pragma unroll
            for (int qi = 0; qi < 4; qi++)
                oacc[ci][qi] = mfma16(vcur[ci], pf[qi], oacc[ci][qi]);
        __builtin_amdgcn_s_setprio(0);
    };

    for (int mb2 = 0; mb2 < 64; ++mb2) {
        ITER(2 * mb2,     vfA, vfB);
        ITER(2 * mb2 + 1, vfB, vfA);
    }

    // reduce denominator across the 16-lane group
#pragma unroll
    for (int r = 0; r < 4; r++) {
        float s = dacc[r];
        s += __shfl_xor(s, 1); s += __shfl_xor(s, 2);
        s += __shfl_xor(s, 4); s += __shfl_xor(s, 8);
        if (l15 == 0) den[w * 16 + lg * 4 + r] = s;
    }
    __syncthreads();

    // epilogue
    for (int qi = 0; qi < 4; qi++) {
        int q = qi * 16 + l15;
        float sc = gamma / den[q];
        int n = qb * 64 + q;
        for (int ci = 0; ci < 4; ci++) {
            int c0 = w * 64 + ci * 16 + lg * 4;
            ushort4 pk;
            pk.x = f2b(oacc[ci][qi][0] * sc);
            pk.y = f2b(oacc[ci][qi][1] * sc);
            pk.z = f2b(oacc[ci][qi][2] * sc);
            pk.w = f2b(oacc[ci][qi][3] * sc);
            *(ushort4*)(Otb + (long)n * 256 + c0) = pk;
            Onb[(long)(c0 + 0) * 4096 + n] = pk.x;
            Onb[(long)(c0 + 1) * 4096 + n] = pk.y;
            Onb[(long)(c0 + 2) * 4096 + n] = pk.z;
            Onb[(long)(c0 + 3) * 4096 + n] = pk.w;
        }
    }
}

// ---------- fused gate (transposed: D cols = n -> coalesced x/out/On) ----------
__global__ __launch_bounds__(256) void gate2_gemm(
    const u16* __restrict__ Ot, const u16* __restrict__ O2t,
    const u16* __restrict__ PQ, const float* __restrict__ r5, const float* __restrict__ r6,
    const u16* __restrict__ On, const u16* __restrict__ O2n,
    const float* __restrict__ x, float* __restrict__ out)
{
    const int bz = blockIdx.z;
    const int n0 = blockIdx.x * 64, c0 = blockIdx.y * 64;
    const int tid = threadIdx.x, lane = tid & 63, w = tid >> 6;
    const int l15 = lane & 15, lg = lane >> 4;
    const int wcc = (w >> 1) * 32, wnn = (w & 1) * 32;
    const long NC = 4096L * 256;
    const long arow = c0 + wcc + l15;
    const u16* pa5 = PQ + arow * 256 + lg * 8;             // P5 rows (c)
    const u16* qa5 = PQ + 65536 + arow * 256 + lg * 8;     // Q5
    const u16* pa6 = PQ + 131072 + arow * 256 + lg * 8;    // P6
    const u16* qa6 = PQ + 196608 + arow * 256 + lg * 8;    // Q6
    const u16* bo  = Ot  + bz * NC + (long)(n0 + wnn + l15) * 256 + lg * 8;
    const u16* bo2 = O2t + bz * NC + (long)(n0 + wnn + l15) * 256 + lg * 8;

    v4f a5[2][2], a6[2][2];
    for (int mi = 0; mi < 2; mi++)
        for (int oi = 0; oi < 2; oi++) {
            a5[mi][oi] = (v4f){0, 0, 0, 0};
            a6[mi][oi] = (v4f){0, 0, 0, 0};
        }
#pragma unroll 4
    for (int k = 0; k < 256; k += 32) {
        v4i bb[2], w5[2], w6[2];
#pragma unroll
        for (int oi = 0; oi < 2; oi++) bb[oi] = *(const v4i*)(bo + (long)oi * 16 * 256 + k);
#pragma unroll
        for (int mi = 0; mi < 2; mi++) {
            w5[mi] = *(const v4i*)(pa5 + (long)mi * 16 * 256 + k);
            w6[mi] = *(const v4i*)(pa6 + (long)mi * 16 * 256 + k);
        }
#pragma unroll
        for (int mi = 0; mi < 2; mi++)
#pragma unroll
            for (int oi = 0; oi < 2; oi++) {
                a5[mi][oi] = mfma16(w5[mi], bb[oi], a5[mi][oi]);
                a6[mi][oi] = mfma16(w6[mi], bb[oi], a6[mi][oi]);
            }
    }
#pragma unroll 4
    for (int k = 0; k < 256; k += 32) {
        v4i bb[2], w5[2], w6[2];
#pragma unroll
        for (int oi = 0; oi < 2; oi++) bb[oi] = *(const v4i*)(bo2 + (long)oi * 16 * 256 + k);
#pragma unroll
        for (int mi = 0; mi < 2; mi++) {
            w5[mi] = *(const v4i*)(qa5 + (long)mi * 16 * 256 + k);
            w6[mi] = *(const v4i*)(qa6 + (long)mi * 16 * 256 + k);
        }
#pragma unroll
        for (int mi = 0; mi < 2; mi++)
#pragma unroll
            for (int oi = 0; oi < 2; oi++) {
                a5[mi][oi] = mfma16(w5[mi], bb[oi], a5[mi][oi]);
                a6[mi][oi] = mfma16(w6[mi], bb[oi], a6[mi][oi]);
            }
    }
    // epilogue: rows = c, cols = n (lane-contiguous n)
    for (int mi = 0; mi < 2; mi++) {
        float r5v[4], r6v[4];
#pragma unroll
        for (int r = 0; r < 4; r++) {
            int c = c0 + wcc + mi * 16 + lg * 4 + r;
            r5v[r] = r5[c]; r6v[r] = r6[c];
        }
        for (int oi = 0; oi < 2; oi++) {
            int n = n0 + wnn + oi * 16 + l15;
#pragma unroll
            for (int r = 0; r < 4; r++) {
                int c = c0 + wcc + mi * 16 + lg * 4 + r;
                long base = bz * NC + (long)c * 4096 + n;
                float ov  = b2f(On[base]);
                float ov2 = b2f(O2n[base]);
                float xv  = x[((long)bz * 256 + c) * 4096 + n];
                float s5 = 1.f / (1.f + __expf(-(a5[mi][oi][r] + r5v[r])));
                float s6 = 1.f / (1.f + __expf(-(a6[mi][oi][r] + r6v[r])));
                float w0 = 1.f / (1.f + __expf(s6 - s5));
                out[((long)bz * 256 + c) * 4096 + n] = w0 * ov + (1.f - w0) * ov2 + xv;
            }
        }
    }
}

// ---------- host ----------
extern "C" void kernel_launch(void* const* d_in, const int* in_sizes, int n_in,
                              void* d_out, int out_size, void* d_ws, size_t ws_size,
                              hipStream_t stream)
{
    const float* x     = (const float*)d_in[0];
    const float* y     = (const float*)d_in[1];
    const float* z     = (const float*)d_in[2];
    const float* m     = (const float*)d_in[3];
    const float* Wv    = (const float*)d_in[4];
    const float* Wv2   = (const float*)d_in[5];
    const float* Wq    = (const float*)d_in[6];
    const float* bq    = (const float*)d_in[7];
    const float* Wk    = (const float*)d_in[8];
    const float* bk    = (const float*)d_in[9];
    const float* Wq2   = (const float*)d_in[10];
    const float* bq2   = (const float*)d_in[11];
    const float* Wk2   = (const float*)d_in[12];
    const float* bk2   = (const float*)d_in[13];
    const float* Win1  = (const float*)d_in[14];
    const float* bin1  = (const float*)d_in[15];
    const float* Win3  = (const float*)d_in[16];
    const float* bin3  = (const float*)d_in[17];
    const float* Wtr   = (const float*)d_in[18];
    const float* btr   = (const float*)d_in[19];
    const float* Wout2 = (const float*)d_in[20];
    const float* bout2 = (const float*)d_in[21];
    const float* Wout3 = (const float*)d_in[22];
    const float* bout3 = (const float*)d_in[23];
    const float* Wfc   = (const float*)d_in[24];
    const float* bfc   = (const float*)d_in[25];
    const float* gamma  = (const float*)d_in[26];
    const float* gamma2 = (const float*)d_in[27];

    char* ws = (char*)d_ws;
    // small area (< 4 MB)
    u16* Wb[6];
    for (int i = 0; i < 6; i++) Wb[i] = (u16*)(ws + (size_t)i * 131072);   // -> 786432
    u16* Wout2b = (u16*)(ws + 786432);     // 128KB
    u16* Wout3b = (u16*)(ws + 917504);     // 128KB
    u16* Win1T  = (u16*)(ws + 1048576);    // 128KB
    u16* Win3T  = (u16*)(ws + 1179648);    // 128KB
    u16* Fb   = (u16*)(ws + 1310720);      // 512KB
    u16* FbT  = (u16*)(ws + 1835008);      // 512KB
    u16* Gk   = (u16*)(ws + 2359296);      // 512KB (per-batch Wk*F')
    u16* PQ   = (u16*)(ws + 2883584);      // 512KB
    u16* Tt   = (u16*)(ws + 3407872);      // 512KB
    float* btr_eff = (float*)(ws + 3932160);
    float* r5 = (float*)(ws + 3934208);
    float* r6 = (float*)(ws + 3935232);
    // big slots
    auto SLOT = [&](int i) { return ws + 4194304 + (size_t)i * 8388608; };
    u16* xt  = (u16*)SLOT(0);
    u16* yt  = (u16*)SLOT(1);
    u16* fmn = (u16*)SLOT(4);
    u16* v2n = (u16*)SLOT(5);
    u16* kt  = (u16*)SLOT(7);
    u16* k2t = (u16*)SLOT(9);
    u16* Ot_ = (u16*)SLOT(6);   // fresh slot (qt dead concept)
    u16* O2n = (u16*)SLOT(8);
    u16* On_ = (u16*)SLOT(2);
    u16* O2t = (u16*)SLOT(3);
    // SLOT(3) doubles as pre-attn scratch (dead once attn writes O2t):
    u16* Wtrb   = (u16*)SLOT(3);                    // 512KB
    float* zv    = (float*)(SLOT(3) + 524288);
    float* mline = (float*)(SLOT(3) + 671744);
    u16* Gv   = (u16*)(SLOT(3) + 1048576);          // 512KB (per-batch F'*Wv)
    u16* Gk2  = (u16*)(SLOT(3) + 1572864);          // 512KB (per-batch Wk*F'*Wv)
    u16* WvT  = (u16*)(SLOT(3) + 2097152);          // 128KB

    const long NC = 4096L * 256, CC = 65536;

    // 1. bf16 weights (plain) + transposed Win1/Win3/Wv
    {
        WCvt wc;
        const float* wsrc[9] = {Wv, Wv2, Wq, Wk, Wq2, Wk2, Wout2, Wout3, Wtr};
        u16* wdst[9] = {Wb[0], Wb[1], Wb[2], Wb[3], Wb[4], Wb[5], Wout2b, Wout3b, Wtrb};
        for (int i = 0; i < 9; i++) { wc.s[i] = wsrc[i]; wc.d[i] = wdst[i]; wc.n[i] = (i == 8) ? 262144 : 65536; }
        cvt_weights<<<dim3(1024, 9), 256, 0, stream>>>(wc);
    }
    cvt_t<<<dim3(8, 8, 3), dim3(32, 8), 0, stream>>>(Win1, Win3, Wv, Win1T, Win3T, WvT);

    // 2. bias folds
    bias_btr<<<512, 256, 0, stream>>>(Wtr, bin1, bin3, btr, btr_eff);
    bias_r56<<<512, 256, 0, stream>>>(Wout2, Wout3, bout2, bout3, btr_eff, r5, r6);

    // 3. transpose+convert x,y
    transpose_cvt<<<dim3(128, 8, 8), dim3(32, 8), 0, stream>>>(x, y, xt, yt);

    // 4. small path
    small_zm<<<dim3(256, 4), 64, 0, stream>>>(z, m, Wv, Wfc, bfc, zv, mline);
    small_F<<<dim3(256, 4), 256, 0, stream>>>(zv, mline, Fb, FbT);

    auto mkdesc = [](const u16* X, int ldx, long xbs, const u16* W, int ldw, long wbs,
                     const float* bias, u16* outT, int ldot, long otbs,
                     u16* outN, int ldon, long onbs, int K, int rows) {
        GDesc g; g.X = X; g.W = W; g.bias = bias; g.outT = outT; g.outN = outN;
        g.xbs = xbs; g.wbs = wbs; g.otbs = otbs; g.onbs = onbs;
        g.ldx = ldx; g.ldw = ldw; g.ldot = ldot; g.ldon = ldon; g.K = K; g.rows = rows;
        return g;
    };

    // 5. T1: tiny composites {Gv = F'*Wv, Gk = Wk*F'} + gate stage-1 {Tt}
    {
        GJob j{}; j.oblk = 2;
        j.d[0] = mkdesc(Fb, 256, CC, WvT, 256, 0, nullptr, Gv, 256, CC, nullptr, 0, 0, 256, 256);
        j.d[1] = mkdesc(Wb[3], 256, 0, FbT, 256, CC, nullptr, Gk, 256, CC, nullptr, 0, 0, 256, 256);
        for (int yy = 0; yy < 4; yy++) {
            const u16* Xw = Wtrb + ((yy >> 1) ? 131072 : 0) + ((yy & 1) ? 256 : 0);
            const u16* Ww = (yy & 1) ? Win3T : Win1T;
            j.d[2 + yy] = mkdesc(Xw, 512, 0, Ww, 256, 0, nullptr,
                                 nullptr, 0, 0, Tt + yy * 65536, 256, 0, 256, 256);
        }
        gemm_tn<<<dim3(2, 12, 4), 256, 0, stream>>>(j);
    }
    // 6. T2: {Gk2 = Gk*Wv} + gate stage-2 {PQ = Wout x T}
    {
        GJob j{}; j.oblk = 2;
        j.d[0] = mkdesc(Gk, 256, CC, WvT, 256, 0, nullptr, Gk2, 256, CC, nullptr, 0, 0, 256, 256);
        for (int yy = 0; yy < 4; yy++) {
            const u16* Xw = (yy >> 1) ? Wout3b : Wout2b;
            j.d[1 + yy] = mkdesc(Xw, 256, 0, Tt + yy * 65536, 256, 0, nullptr,
                                 PQ + yy * 65536, 256, 0, nullptr, 0, 0, 256, 256);
        }
        gemm_tn<<<dim3(2, 10, 4), 256, 0, stream>>>(j);
    }
    // 7. BIG: {k2t, v2n from xt} + {fmn = Gv*y, kt = Gk2*y + bk from yt}
    {
        GJob j{}; j.oblk = 2;
        j.d[0] = mkdesc(xt, 256, NC, Wb[5], 256, 0, bk2, k2t, 256, NC, nullptr, 0, 0, 256, 4096);
        j.d[1] = mkdesc(xt, 256, NC, Wb[1], 256, 0, nullptr, nullptr, 0, 0, v2n, 4096, NC, 256, 4096);
        j.d[2] = mkdesc(yt, 256, NC, Gv,  256, CC, nullptr, nullptr, 0, 0, fmn, 4096, NC, 256, 4096);
        j.d[3] = mkdesc(yt, 256, NC, Gk2, 256, CC, bk, kt, 256, NC, nullptr, 0, 0, 256, 4096);
        gemm_tn<<<dim3(32, 8, 4), 256, 0, stream>>>(j);
    }

    // 8. attention (Q/Q2 projected in-kernel)
    attn_kernel<<<dim3(512), 256, 0, stream>>>(xt, Wb[2], bq, Wb[4], bq2,
                                               kt, fmn, Ot_, On_, gamma,
                                               k2t, v2n, O2t, O2n, gamma2);

    // 9. fused gate epilogue
    gate2_gemm<<<dim3(64, 4, 4), 256, 0, stream>>>(Ot_, O2t, PQ, r5, r6,
                                                   On_, O2n, x, (float*)d_out);
}

// Round 16
// 326.220 us; speedup vs baseline: 1.0777x; 1.0777x over previous
//
#include <hip/hip_runtime.h>

typedef unsigned short u16;
typedef unsigned int   u32;
typedef int   v4i __attribute__((ext_vector_type(4)));
typedef float v4f __attribute__((ext_vector_type(4)));

// ---------- helpers ----------
__device__ __forceinline__ float b2f(u16 v) {
    union { unsigned u; float f; } t; t.u = ((unsigned)v) << 16; return t.f;
}
__device__ __forceinline__ u16 f2b(float f) {
    union { float f; unsigned u; } t; t.f = f;
    unsigned r = (t.u + 0x7FFFu + ((t.u >> 16) & 1u)) >> 16;
    return (u16)r;
}
__device__ __forceinline__ u16 f2b_trunc(float f) {
    union { float f; unsigned u; } t; t.f = f;
    return (u16)(t.u >> 16);
}
__device__ __forceinline__ v4f mfma16(v4i a, v4i b, v4f c) {
    asm("v_mfma_f32_16x16x32_bf16 %0, %1, %2, %0" : "+v"(c) : "v"(a), "v"(b));
    return c;
}
__device__ __forceinline__ void gload16(const u16* g, u16* l) {
    __builtin_amdgcn_global_load_lds(
        (const __attribute__((address_space(1))) unsigned int*)g,
        (__attribute__((address_space(3))) unsigned int*)l,
        16, 0, 0);
}

// ---------- weight f32->bf16 convert (plain) ----------
struct WCvt { const float* s[9]; u16* d[9]; int n[9]; };
__global__ void cvt_weights(WCvt p) {
    int wi = blockIdx.y;
    int i = blockIdx.x * 256 + threadIdx.x;
    if (i < p.n[wi]) p.d[wi][i] = f2b(p.s[wi][i]);
}

// ---------- transposed convert (256x256): Win1, Win3, Wv ----------
__global__ void cvt_t(const float* __restrict__ W1, const float* __restrict__ W3,
                      const float* __restrict__ Wv,
                      u16* __restrict__ T1, u16* __restrict__ T3, u16* __restrict__ Tv)
{
    const int zz = blockIdx.z;
    const float* src = (zz == 0) ? W1 : (zz == 1) ? W3 : Wv;
    u16* dst = (zz == 0) ? T1 : (zz == 1) ? T3 : Tv;
    __shared__ float t[32][33];
    const int r0 = blockIdx.x * 32, c0 = blockIdx.y * 32;
    const int tx = threadIdx.x, ty = threadIdx.y;
#pragma unroll
    for (int i = 0; i < 4; i++)
        t[ty + i * 8][tx] = src[(long)(r0 + ty + i * 8) * 256 + c0 + tx];
    __syncthreads();
#pragma unroll
    for (int i = 0; i < 4; i++)
        dst[(long)(c0 + ty + i * 8) * 256 + r0 + tx] = f2b(t[tx][ty + i * 8]);
}

// ---------- bias folds (parallel reductions) ----------
__global__ void bias_btr(const float* __restrict__ Wtr, const float* __restrict__ bin1,
                         const float* __restrict__ bin3, const float* __restrict__ btr,
                         float* __restrict__ btr_eff)
{
    const int j = blockIdx.x, k = threadIdx.x;   // 512 x 256
    float v = Wtr[(long)j * 512 + k] * bin1[k] + Wtr[(long)j * 512 + 256 + k] * bin3[k];
    v += __shfl_xor(v, 1); v += __shfl_xor(v, 2); v += __shfl_xor(v, 4);
    v += __shfl_xor(v, 8); v += __shfl_xor(v, 16); v += __shfl_xor(v, 32);
    __shared__ float part[4];
    if ((k & 63) == 0) part[k >> 6] = v;
    __syncthreads();
    if (k == 0) btr_eff[j] = btr[j] + part[0] + part[1] + part[2] + part[3];
}

__global__ void bias_r56(const float* __restrict__ Wout2, const float* __restrict__ Wout3,
                         const float* __restrict__ bout2, const float* __restrict__ bout3,
                         const float* __restrict__ btr_eff,
                         float* __restrict__ r5, float* __restrict__ r6)
{
    const int j = blockIdx.x, k = threadIdx.x;   // 512 x 256
    float v = (j < 256) ? Wout2[(long)j * 256 + k] * btr_eff[k]
                        : Wout3[(long)(j - 256) * 256 + k] * btr_eff[256 + k];
    v += __shfl_xor(v, 1); v += __shfl_xor(v, 2); v += __shfl_xor(v, 4);
    v += __shfl_xor(v, 8); v += __shfl_xor(v, 16); v += __shfl_xor(v, 32);
    __shared__ float part[4];
    if ((k & 63) == 0) part[k >> 6] = v;
    __syncthreads();
    if (k == 0) {
        float s = part[0] + part[1] + part[2] + part[3];
        if (j < 256) r5[j] = bout2[j] + s;
        else         r6[j - 256] = bout3[j - 256] + s;
    }
}

// ---------- transpose+convert x,y ----------
__global__ __launch_bounds__(256) void transpose_cvt(
    const float* __restrict__ x, const float* __restrict__ y,
    u16* __restrict__ xt, u16* __restrict__ yt)
{
    const int z = blockIdx.z, t = z >> 2, b = z & 3;
    const float* src = t ? y : x;
    u16* dst = t ? yt : xt;
    __shared__ float tile[32][33];
    const int nt = blockIdx.x * 32, ct = blockIdx.y * 32;
    const int tx = threadIdx.x, ty = threadIdx.y;
#pragma unroll
    for (int i = 0; i < 4; i++)
        tile[ty + i * 8][tx] = src[((long)b * 256 + ct + ty + i * 8) * 4096 + nt + tx];
    __syncthreads();
#pragma unroll
    for (int i = 0; i < 4; i++)
        dst[((long)b * 4096 + nt + ty + i * 8) * 256 + ct + tx] = f2b(tile[tx][ty + i * 8]);
}

// ---------- small path ----------
__global__ void small_zm(const float* __restrict__ z, const float* __restrict__ m,
                         const float* __restrict__ Wv, const float* __restrict__ Wfc,
                         const float* __restrict__ bfc,
                         float* __restrict__ zv, float* __restrict__ mline)
{
    const int o = blockIdx.x, b = blockIdx.y, tid = threadIdx.x; // block 64
    __shared__ float wrow[256];
    __shared__ float mvs[9];
    for (int i = tid; i < 256; i += 64) wrow[i] = Wv[o * 256 + i];
    __syncthreads();
    if (tid < 36) {
        float s = 0.f;
        for (int c = 0; c < 256; c++) s += wrow[c] * z[((long)b * 256 + c) * 36 + tid];
        zv[((long)b * 256 + o) * 36 + tid] = s;
    }
    if (tid < 9) {
        float s = 0.f;
        for (int c = 0; c < 256; c++) s += wrow[c] * m[((long)b * 256 + c) * 9 + tid];
        mvs[tid] = s;
    }
    __syncthreads();
    if (tid < 36) {
        float s = bfc[tid];
        for (int k = 0; k < 9; k++) s += mvs[k] * Wfc[tid * 9 + k];
        mline[((long)b * 256 + o) * 36 + tid] = s;
    }
}

__global__ void small_F(const float* __restrict__ zv, const float* __restrict__ mline,
                        u16* __restrict__ Fb, u16* __restrict__ FbT)
{
    const int c = blockIdx.x, b = blockIdx.y, d = threadIdx.x;
    const float* zr = zv + ((long)b * 256 + c) * 36;
    const float* mr = mline + ((long)b * 256 + d) * 36;
    float s = (c == d) ? 1.f : 0.f;
    for (int n = 0; n < 36; n++) s += zr[n] * mr[n];
    u16 v = f2b(s);
    Fb[((long)b * 256 + c) * 256 + d] = v;
    FbT[((long)b * 256 + d) * 256 + c] = v;
}

// ---------- merged GEMM: LDS-staged (m97 structure), BK=32, dbuf ----------
struct GDesc {
    const u16* X; const u16* W; const float* bias;
    u16* outT; u16* outN;
    long xbs, wbs, otbs, onbs;
    int ldx, ldw, ldot, ldon, K, rows;
};
struct GJob { GDesc d[12]; int oblk; };

__global__ __launch_bounds__(256) void gemm_tn(GJob j) {
    const int di = blockIdx.y / j.oblk;
    const int o0 = (blockIdx.y % j.oblk) * 128;
    const GDesc g = j.d[di];
    const int b = blockIdx.z;
    const int n0 = blockIdx.x * 128;
    if (n0 >= g.rows) return;
    const int tid = threadIdx.x, lane = tid & 63, w = tid >> 6;
    const int l15 = lane & 15, lg = lane >> 4;
    const int wr = (w >> 1) * 64, wc = (w & 1) * 64;

    __shared__ __align__(16) u16 As[2][4096];   // 128 x 32 bf16, dbuf (16 KB)
    __shared__ __align__(16) u16 Bs[2][4096];   // 128 x 32 bf16, dbuf (16 KB)

    const int sr = w * 32 + (lane >> 2);
    const int sc = (lane & 3) * 8;
    const u16* Xb_ = g.X + b * g.xbs;
    const u16* Wp_ = g.W + b * g.wbs;

    auto STAGE = [&](int buf, int ks) {
#pragma unroll
        for (int i = 0; i < 2; i++) {
            gload16(Xb_ + (long)(n0 + sr + i * 16) * g.ldx + ks * 32 + sc,
                    &As[buf][w * 1024 + i * 512]);
            gload16(Wp_ + (long)(o0 + sr + i * 16) * g.ldw + ks * 32 + sc,
                    &Bs[buf][w * 1024 + i * 512]);
        }
    };

    v4f acc[4][4];
    for (int oi = 0; oi < 4; oi++) {
        float bv = g.bias ? g.bias[o0 + wc + oi * 16 + l15] : 0.f;
        for (int mi = 0; mi < 4; mi++) acc[mi][oi] = (v4f){bv, bv, bv, bv};
    }

    const int steps = g.K >> 5;
    STAGE(0, 0);
    __syncthreads();
    for (int ks = 0; ks < steps; ks++) {
        const int cur = ks & 1;
        if (ks + 1 < steps) STAGE(cur ^ 1, ks + 1);
        v4i a[4], bb[4];
#pragma unroll
        for (int mi = 0; mi < 4; mi++)
            a[mi] = *(const v4i*)&As[cur][(wr + mi * 16 + l15) * 32 + lg * 8];
#pragma unroll
        for (int oi = 0; oi < 4; oi++)
            bb[oi] = *(const v4i*)&Bs[cur][(wc + oi * 16 + l15) * 32 + lg * 8];
#pragma unroll
        for (int mi = 0; mi < 4; mi++)
#pragma unroll
            for (int oi = 0; oi < 4; oi++)
                acc[mi][oi] = mfma16(a[mi], bb[oi], acc[mi][oi]);
        __syncthreads();
    }

    for (int mi = 0; mi < 4; mi++)
        for (int oi = 0; oi < 4; oi++) {
            int nn = n0 + wr + mi * 16 + lg * 4;
            int oo = o0 + wc + oi * 16 + l15;
            if (g.outT) {
                u16* p = g.outT + b * g.otbs + (long)nn * g.ldot + oo;
#pragma unroll
                for (int r = 0; r < 4; r++) p[(long)r * g.ldot] = f2b(acc[mi][oi][r]);
            }
            if (g.outN) {
                ushort4 pk;
                pk.x = f2b(acc[mi][oi][0]); pk.y = f2b(acc[mi][oi][1]);
                pk.z = f2b(acc[mi][oi][2]); pk.w = f2b(acc[mi][oi][3]);
                *(ushort4*)(g.outN + b * g.onbs + (long)oo * g.ldon + nn) = pk;
            }
        }
}

// ---------- fused attention (round-9 structure, 188 us): 4 waves, depth-4 K pipeline ----------
__global__ __launch_bounds__(256) void attn_kernel(
    const u16* __restrict__ qtA, const u16* __restrict__ ktA, const u16* __restrict__ vA,
    u16* __restrict__ otA, u16* __restrict__ onA, const float* __restrict__ gA,
    const u16* __restrict__ qtB, const u16* __restrict__ ktB, const u16* __restrict__ vB,
    u16* __restrict__ otB, u16* __restrict__ onB, const float* __restrict__ gB)
{
    // XCD swizzle: all 64 q-blocks of one (branch,batch) share an XCD (wgid%8)
    const int wg = blockIdx.x;
    const int qb = wg >> 3, code = wg & 7;
    const int br = code & 1, b = code >> 1;
    const u16* Qt = br ? qtB : qtA;
    const u16* Kt = br ? ktB : ktA;
    const u16* V  = br ? vB  : vA;
    u16* Ot = br ? otB : otA;
    u16* On = br ? onB : onA;
    const float gamma = br ? gB[0] : gA[0];
    const long bs = (long)4096 * 256;
    const u16* Qb = Qt + b * bs;
    const u16* Kb = Kt + b * bs;
    const u16* Vb = V + b * bs;
    u16* Otb = Ot + b * bs;
    u16* Onb = On + b * bs;

    const int tid = threadIdx.x, lane = tid & 63, w = tid >> 6;
    const int l15 = lane & 15, lg = lane >> 4;

    __shared__ __align__(16) u16 Ksh[4][8192];   // 4 x (32x256 bf16) = 64KB
    __shared__ __align__(16) u16 P[2][64][56];   // dbuf, 112B rows
    __shared__ float den[64];

    v4i qf[8];
    const u16* qp = Qb + (long)(qb * 64 + w * 16 + l15) * 256 + lg * 8;
#pragma unroll
    for (int ks = 0; ks < 8; ks++) qf[ks] = *(const v4i*)(qp + ks * 32);

    v4f oacc[4][4];
    for (int ci = 0; ci < 4; ci++)
        for (int qi = 0; qi < 4; qi++) oacc[ci][qi] = (v4f){0.f, 0.f, 0.f, 0.f};
    float dacc[4] = {0.f, 0.f, 0.f, 0.f};

    const u16* vb = Vb + (long)(w * 64 + l15) * 4096 + lg * 8;
    v4i vfA[4], vfB[4];

    const int srow = w * 8 + (lane >> 5);
    const int scolB = (lane & 31) * 16;

    auto STAGE = [&](int buf, int t) {
        const u16* base = Kb + (long)t * 8192;
        u16* lb = &Ksh[buf][w * 2048];
#pragma unroll
        for (int i = 0; i < 4; i++) {
            int row = srow + i * 2;
            int colB = scolB ^ ((row & 7) << 4);   // inverse swizzle on SOURCE
            gload16(base + row * 256 + (colB >> 1), lb + i * 512);
        }
    };
    auto VLOAD = [&](v4i (&vf)[4], int t) {
#pragma unroll
        for (int ci = 0; ci < 4; ci++)
            vf[ci] = *(const v4i*)(vb + (long)ci * 16 * 4096 + t * 32);
    };

    STAGE(0, 0);
    STAGE(1, 1);
    STAGE(2, 2);
    VLOAD(vfA, 0);
    asm volatile("s_waitcnt vmcnt(12)" ::: "memory");  // STAGE(0) complete
    __builtin_amdgcn_s_barrier();
    __builtin_amdgcn_sched_barrier(0);

    auto ITER = [&](int mb, v4i (&vcur)[4], v4i (&vnxt)[4]) {
        const u16* kb = &Ksh[mb & 3][0];
        u16* Pc = &P[mb & 1][0][0];

        // QK^T: L[16 own q][32 m], 4 independent chains
        v4f l0a = {0,0,0,0}, l0b = {0,0,0,0}, l1a = {0,0,0,0}, l1b = {0,0,0,0};
        __builtin_amdgcn_s_setprio(1);
#pragma unroll
        for (int ks = 0; ks < 4; ks++) {
            int c0 = (ks * 64 + lg * 16) ^ ((l15 & 7) << 4);   // swizzled READ
            v4i k0 = *(const v4i*)(kb + l15 * 256 + (c0 >> 1));
            v4i k1 = *(const v4i*)(kb + (16 + l15) * 256 + (c0 >> 1));
            l0a = mfma16(qf[ks], k0, l0a);
            l1a = mfma16(qf[ks], k1, l1a);
        }
#pragma unroll
        for (int ks = 4; ks < 8; ks++) {
            int c0 = (ks * 64 + lg * 16) ^ ((l15 & 7) << 4);
            v4i k0 = *(const v4i*)(kb + l15 * 256 + (c0 >> 1));
            v4i k1 = *(const v4i*)(kb + (16 + l15) * 256 + (c0 >> 1));
            l0b = mfma16(qf[ks], k0, l0b);
            l1b = mfma16(qf[ks], k1, l1b);
        }
        __builtin_amdgcn_s_setprio(0);
        v4f lacc0 = l0a + l0b, lacc1 = l1a + l1b;

        // exp -> P (b16 stores), denominator accumulation
#pragma unroll
        for (int r = 0; r < 4; r++) {
            float e0 = __expf(lacc0[r]);
            float e1 = __expf(lacc1[r]);
            dacc[r] += e0 + e1;
            Pc[(w * 16 + lg * 4 + r) * 56 + l15]      = f2b_trunc(e0);
            Pc[(w * 16 + lg * 4 + r) * 56 + 16 + l15] = f2b_trunc(e1);
        }

        // prefetch: V one iter ahead (regs), K three iters ahead (LDS)
        if (mb < 127) VLOAD(vnxt, mb + 1);
        if (mb < 125) STAGE((mb + 3) & 3, mb + 3);

        // single barrier: seal P (lgkm) + STAGE(mb+1) complete (counted vmcnt)
        if (mb <= 124)      asm volatile("s_waitcnt vmcnt(12) lgkmcnt(0)" ::: "memory");
        else if (mb == 125) asm volatile("s_waitcnt vmcnt(8) lgkmcnt(0)" ::: "memory");
        else if (mb == 126) asm volatile("s_waitcnt vmcnt(4) lgkmcnt(0)" ::: "memory");
        else                asm volatile("s_waitcnt vmcnt(0) lgkmcnt(0)" ::: "memory");
        __builtin_amdgcn_s_barrier();
        __builtin_amdgcn_sched_barrier(0);

        // PV: wave w owns channels [w*64, +64), k-dim = 32 keys
        v4i pf[4];
#pragma unroll
        for (int qi = 0; qi < 4; qi++)
            pf[qi] = *(const v4i*)(Pc + (qi * 16 + l15) * 56 + lg * 8);
        __builtin_amdgcn_s_setprio(1);
#pragma unroll
        for (int ci = 0; ci < 4; ci++)
#pragma unroll
            for (int qi = 0; qi < 4; qi++)
                oacc[ci][qi] = mfma16(vcur[ci], pf[qi], oacc[ci][qi]);
        __builtin_amdgcn_s_setprio(0);
    };

    for (int mb2 = 0; mb2 < 64; ++mb2) {
        ITER(2 * mb2,     vfA, vfB);
        ITER(2 * mb2 + 1, vfB, vfA);
    }

    // reduce denominator across the 16-lane group
#pragma unroll
    for (int r = 0; r < 4; r++) {
        float s = dacc[r];
        s += __shfl_xor(s, 1); s += __shfl_xor(s, 2);
        s += __shfl_xor(s, 4); s += __shfl_xor(s, 8);
        if (l15 == 0) den[w * 16 + lg * 4 + r] = s;
    }
    __syncthreads();

    // epilogue
    for (int qi = 0; qi < 4; qi++) {
        int q = qi * 16 + l15;
        float sc = gamma / den[q];
        int n = qb * 64 + q;
        for (int ci = 0; ci < 4; ci++) {
            int c0 = w * 64 + ci * 16 + lg * 4;
            ushort4 pk;
            pk.x = f2b(oacc[ci][qi][0] * sc);
            pk.y = f2b(oacc[ci][qi][1] * sc);
            pk.z = f2b(oacc[ci][qi][2] * sc);
            pk.w = f2b(oacc[ci][qi][3] * sc);
            *(ushort4*)(Otb + (long)n * 256 + c0) = pk;
            Onb[(long)(c0 + 0) * 4096 + n] = pk.x;
            Onb[(long)(c0 + 1) * 4096 + n] = pk.y;
            Onb[(long)(c0 + 2) * 4096 + n] = pk.z;
            Onb[(long)(c0 + 3) * 4096 + n] = pk.w;
        }
    }
}

// ---------- fused gate (transposed: D cols = n -> coalesced x/out/On) ----------
__global__ __launch_bounds__(256) void gate2_gemm(
    const u16* __restrict__ Ot, const u16* __restrict__ O2t,
    const u16* __restrict__ PQ, const float* __restrict__ r5, const float* __restrict__ r6,
    const u16* __restrict__ On, const u16* __restrict__ O2n,
    const float* __restrict__ x, float* __restrict__ out)
{
    const int bz = blockIdx.z;
    const int n0 = blockIdx.x * 64, c0 = blockIdx.y * 64;
    const int tid = threadIdx.x, lane = tid & 63, w = tid >> 6;
    const int l15 = lane & 15, lg = lane >> 4;
    const int wcc = (w >> 1) * 32, wnn = (w & 1) * 32;
    const long NC = 4096L * 256;
    const long arow = c0 + wcc + l15;
    const u16* pa5 = PQ + arow * 256 + lg * 8;             // P5 rows (c)
    const u16* qa5 = PQ + 65536 + arow * 256 + lg * 8;     // Q5
    const u16* pa6 = PQ + 131072 + arow * 256 + lg * 8;    // P6
    const u16* qa6 = PQ + 196608 + arow * 256 + lg * 8;    // Q6
    const u16* bo  = Ot  + bz * NC + (long)(n0 + wnn + l15) * 256 + lg * 8;
    const u16* bo2 = O2t + bz * NC + (long)(n0 + wnn + l15) * 256 + lg * 8;

    v4f a5[2][2], a6[2][2];
    for (int mi = 0; mi < 2; mi++)
        for (int oi = 0; oi < 2; oi++) {
            a5[mi][oi] = (v4f){0, 0, 0, 0};
            a6[mi][oi] = (v4f){0, 0, 0, 0};
        }
#pragma unroll 4
    for (int k = 0; k < 256; k += 32) {
        v4i bb[2], w5[2], w6[2];
#pragma unroll
        for (int oi = 0; oi < 2; oi++) bb[oi] = *(const v4i*)(bo + (long)oi * 16 * 256 + k);
#pragma unroll
        for (int mi = 0; mi < 2; mi++) {
            w5[mi] = *(const v4i*)(pa5 + (long)mi * 16 * 256 + k);
            w6[mi] = *(const v4i*)(pa6 + (long)mi * 16 * 256 + k);
        }
#pragma unroll
        for (int mi = 0; mi < 2; mi++)
#pragma unroll
            for (int oi = 0; oi < 2; oi++) {
                a5[mi][oi] = mfma16(w5[mi], bb[oi], a5[mi][oi]);
                a6[mi][oi] = mfma16(w6[mi], bb[oi], a6[mi][oi]);
            }
    }
#pragma unroll 4
    for (int k = 0; k < 256; k += 32) {
        v4i bb[2], w5[2], w6[2];
#pragma unroll
        for (int oi = 0; oi < 2; oi++) bb[oi] = *(const v4i*)(bo2 + (long)oi * 16 * 256 + k);
#pragma unroll
        for (int mi = 0; mi < 2; mi++) {
            w5[mi] = *(const v4i*)(qa5 + (long)mi * 16 * 256 + k);
            w6[mi] = *(const v4i*)(qa6 + (long)mi * 16 * 256 + k);
        }
#pragma unroll
        for (int mi = 0; mi < 2; mi++)
#pragma unroll
            for (int oi = 0; oi < 2; oi++) {
                a5[mi][oi] = mfma16(w5[mi], bb[oi], a5[mi][oi]);
                a6[mi][oi] = mfma16(w6[mi], bb[oi], a6[mi][oi]);
            }
    }
    // epilogue: rows = c, cols = n (lane-contiguous n)
    for (int mi = 0; mi < 2; mi++) {
        float r5v[4], r6v[4];
#pragma unroll
        for (int r = 0; r < 4; r++) {
            int c = c0 + wcc + mi * 16 + lg * 4 + r;
            r5v[r] = r5[c]; r6v[r] = r6[c];
        }
        for (int oi = 0; oi < 2; oi++) {
            int n = n0 + wnn + oi * 16 + l15;
#pragma unroll
            for (int r = 0; r < 4; r++) {
                int c = c0 + wcc + mi * 16 + lg * 4 + r;
                long base = bz * NC + (long)c * 4096 + n;
                float ov  = b2f(On[base]);
                float ov2 = b2f(O2n[base]);
                float xv  = x[((long)bz * 256 + c) * 4096 + n];
                float s5 = 1.f / (1.f + __expf(-(a5[mi][oi][r] + r5v[r])));
                float s6 = 1.f / (1.f + __expf(-(a6[mi][oi][r] + r6v[r])));
                float w0 = 1.f / (1.f + __expf(s6 - s5));
                out[((long)bz * 256 + c) * 4096 + n] = w0 * ov + (1.f - w0) * ov2 + xv;
            }
        }
    }
}

// ---------- host ----------
extern "C" void kernel_launch(void* const* d_in, const int* in_sizes, int n_in,
                              void* d_out, int out_size, void* d_ws, size_t ws_size,
                              hipStream_t stream)
{
    const float* x     = (const float*)d_in[0];
    const float* y     = (const float*)d_in[1];
    const float* z     = (const float*)d_in[2];
    const float* m     = (const float*)d_in[3];
    const float* Wv    = (const float*)d_in[4];
    const float* Wv2   = (const float*)d_in[5];
    const float* Wq    = (const float*)d_in[6];
    const float* bq    = (const float*)d_in[7];
    const float* Wk    = (const float*)d_in[8];
    const float* bk    = (const float*)d_in[9];
    const float* Wq2   = (const float*)d_in[10];
    const float* bq2   = (const float*)d_in[11];
    const float* Wk2   = (const float*)d_in[12];
    const float* bk2   = (const float*)d_in[13];
    const float* Win1  = (const float*)d_in[14];
    const float* bin1  = (const float*)d_in[15];
    const float* Win3  = (const float*)d_in[16];
    const float* bin3  = (const float*)d_in[17];
    const float* Wtr   = (const float*)d_in[18];
    const float* btr   = (const float*)d_in[19];
    const float* Wout2 = (const float*)d_in[20];
    const float* bout2 = (const float*)d_in[21];
    const float* Wout3 = (const float*)d_in[22];
    const float* bout3 = (const float*)d_in[23];
    const float* Wfc   = (const float*)d_in[24];
    const float* bfc   = (const float*)d_in[25];
    const float* gamma  = (const float*)d_in[26];
    const float* gamma2 = (const float*)d_in[27];

    char* ws = (char*)d_ws;
    // small area (< 4 MB)
    u16* Wb[6];
    for (int i = 0; i < 6; i++) Wb[i] = (u16*)(ws + (size_t)i * 131072);   // -> 786432
    u16* Wout2b = (u16*)(ws + 786432);     // 128KB
    u16* Wout3b = (u16*)(ws + 917504);     // 128KB
    u16* Win1T  = (u16*)(ws + 1048576);    // 128KB
    u16* Win3T  = (u16*)(ws + 1179648);    // 128KB
    u16* Fb   = (u16*)(ws + 1310720);      // 512KB
    u16* FbT  = (u16*)(ws + 1835008);      // 512KB
    u16* Gk   = (u16*)(ws + 2359296);      // 512KB (per-batch Wk*F')
    u16* PQ   = (u16*)(ws + 2883584);      // 512KB
    u16* Tt   = (u16*)(ws + 3407872);      // 512KB
    float* btr_eff = (float*)(ws + 3932160);
    float* r5 = (float*)(ws + 3934208);
    float* r6 = (float*)(ws + 3935232);
    // big slots
    auto SLOT = [&](int i) { return ws + 4194304 + (size_t)i * 8388608; };
    u16* xt  = (u16*)SLOT(0);
    u16* yt  = (u16*)SLOT(1);
    u16* fmn = (u16*)SLOT(4);
    u16* v2n = (u16*)SLOT(5);
    u16* qt  = (u16*)SLOT(6);
    u16* kt  = (u16*)SLOT(7);
    u16* q2t = (u16*)SLOT(8);
    u16* k2t = (u16*)SLOT(9);
    u16* O2n = (u16*)SLOT(0);   // xt dead after BIG
    u16* Ot_ = (u16*)SLOT(1);   // yt dead after BIG
    u16* On_ = (u16*)SLOT(2);
    u16* O2t = (u16*)SLOT(3);
    // SLOT(3) doubles as pre-attn scratch (dead once attn writes O2t):
    u16* Wtrb   = (u16*)SLOT(3);                    // 512KB
    float* zv    = (float*)(SLOT(3) + 524288);
    float* mline = (float*)(SLOT(3) + 671744);
    u16* Gv   = (u16*)(SLOT(3) + 1048576);          // 512KB (per-batch F'*Wv)
    u16* Gk2  = (u16*)(SLOT(3) + 1572864);          // 512KB (per-batch Wk*F'*Wv)
    u16* WvT  = (u16*)(SLOT(3) + 2097152);          // 128KB

    const long NC = 4096L * 256, CC = 65536;

    // 1. bf16 weights (plain) + transposed Win1/Win3/Wv
    {
        WCvt wc;
        const float* wsrc[9] = {Wv, Wv2, Wq, Wk, Wq2, Wk2, Wout2, Wout3, Wtr};
        u16* wdst[9] = {Wb[0], Wb[1], Wb[2], Wb[3], Wb[4], Wb[5], Wout2b, Wout3b, Wtrb};
        for (int i = 0; i < 9; i++) { wc.s[i] = wsrc[i]; wc.d[i] = wdst[i]; wc.n[i] = (i == 8) ? 262144 : 65536; }
        cvt_weights<<<dim3(1024, 9), 256, 0, stream>>>(wc);
    }
    cvt_t<<<dim3(8, 8, 3), dim3(32, 8), 0, stream>>>(Win1, Win3, Wv, Win1T, Win3T, WvT);

    // 2. bias folds
    bias_btr<<<512, 256, 0, stream>>>(Wtr, bin1, bin3, btr, btr_eff);
    bias_r56<<<512, 256, 0, stream>>>(Wout2, Wout3, bout2, bout3, btr_eff, r5, r6);

    // 3. transpose+convert x,y
    transpose_cvt<<<dim3(128, 8, 8), dim3(32, 8), 0, stream>>>(x, y, xt, yt);

    // 4. small path
    small_zm<<<dim3(256, 4), 64, 0, stream>>>(z, m, Wv, Wfc, bfc, zv, mline);
    small_F<<<dim3(256, 4), 256, 0, stream>>>(zv, mline, Fb, FbT);

    auto mkdesc = [](const u16* X, int ldx, long xbs, const u16* W, int ldw, long wbs,
                     const float* bias, u16* outT, int ldot, long otbs,
                     u16* outN, int ldon, long onbs, int K, int rows) {
        GDesc g; g.X = X; g.W = W; g.bias = bias; g.outT = outT; g.outN = outN;
        g.xbs = xbs; g.wbs = wbs; g.otbs = otbs; g.onbs = onbs;
        g.ldx = ldx; g.ldw = ldw; g.ldot = ldot; g.ldon = ldon; g.K = K; g.rows = rows;
        return g;
    };

    // 5. T1: tiny composites {Gv = F'*Wv, Gk = Wk*F'} + gate stage-1 {Tt}
    {
        GJob j{}; j.oblk = 2;
        j.d[0] = mkdesc(Fb, 256, CC, WvT, 256, 0, nullptr, Gv, 256, CC, nullptr, 0, 0, 256, 256);
        j.d[1] = mkdesc(Wb[3], 256, 0, FbT, 256, CC, nullptr, Gk, 256, CC, nullptr, 0, 0, 256, 256);
        for (int yy = 0; yy < 4; yy++) {
            const u16* Xw = Wtrb + ((yy >> 1) ? 131072 : 0) + ((yy & 1) ? 256 : 0);
            const u16* Ww = (yy & 1) ? Win3T : Win1T;
            j.d[2 + yy] = mkdesc(Xw, 512, 0, Ww, 256, 0, nullptr,
                                 nullptr, 0, 0, Tt + yy * 65536, 256, 0, 256, 256);
        }
        gemm_tn<<<dim3(2, 12, 4), 256, 0, stream>>>(j);
    }
    // 6. T2: {Gk2 = Gk*Wv} + gate stage-2 {PQ = Wout x T}
    {
        GJob j{}; j.oblk = 2;
        j.d[0] = mkdesc(Gk, 256, CC, WvT, 256, 0, nullptr, Gk2, 256, CC, nullptr, 0, 0, 256, 256);
        for (int yy = 0; yy < 4; yy++) {
            const u16* Xw = (yy >> 1) ? Wout3b : Wout2b;
            j.d[1 + yy] = mkdesc(Xw, 256, 0, Tt + yy * 65536, 256, 0, nullptr,
                                 PQ + yy * 65536, 256, 0, nullptr, 0, 0, 256, 256);
        }
        gemm_tn<<<dim3(2, 10, 4), 256, 0, stream>>>(j);
    }
    // 7. BIG: {qt, q2t, k2t, v2n from xt} + {fmn = Gv*y, kt = Gk2*y + bk from yt}
    {
        GJob j{}; j.oblk = 2;
        j.d[0] = mkdesc(xt, 256, NC, Wb[2], 256, 0, bq,  qt,  256, NC, nullptr, 0, 0, 256, 4096);
        j.d[1] = mkdesc(xt, 256, NC, Wb[4], 256, 0, bq2, q2t, 256, NC, nullptr, 0, 0, 256, 4096);
        j.d[2] = mkdesc(xt, 256, NC, Wb[5], 256, 0, bk2, k2t, 256, NC, nullptr, 0, 0, 256, 4096);
        j.d[3] = mkdesc(xt, 256, NC, Wb[1], 256, 0, nullptr, nullptr, 0, 0, v2n, 4096, NC, 256, 4096);
        j.d[4] = mkdesc(yt, 256, NC, Gv,  256, CC, nullptr, nullptr, 0, 0, fmn, 4096, NC, 256, 4096);
        j.d[5] = mkdesc(yt, 256, NC, Gk2, 256, CC, bk, kt, 256, NC, nullptr, 0, 0, 256, 4096);
        gemm_tn<<<dim3(32, 12, 4), 256, 0, stream>>>(j);
    }

    // 8. attention (round-9 structure)
    attn_kernel<<<dim3(512), 256, 0, stream>>>(qt, kt, fmn, Ot_, On_, gamma,
                                               q2t, k2t, v2n, O2t, O2n, gamma2);

    // 9. fused gate epilogue
    gate2_gemm<<<dim3(64, 4, 4), 256, 0, stream>>>(Ot_, O2t, PQ, r5, r6,
                                                   On_, O2n, x, (float*)d_out);
}